// Round 1
// baseline (13.326 us; speedup 1.0000x reference)
//
#include <hip/hip_runtime.h>
#include <hip/hip_bf16.h>

// Embedding via one-hot @ W.T  ==  gather of W columns.
// X: [B=2, S=2048] int32 indices in [0, 32000)
// W: [E=128, V=32000] float32 (nn.Linear weight layout)
// out[b,s,e] = W[e, X[b,s]]  -> out is [B, S, E] float32, E contiguous.

#define VOCAB 32000
#define EMBED 128
#define NTOK  4096          // 2 * 2048
#define VEC   4             // float4 per thread
#define THREADS_PER_TOK (EMBED / VEC)   // 32

__global__ __launch_bounds__(256) void embed_gather_kernel(
        const int* __restrict__ X,
        const float* __restrict__ W,
        float* __restrict__ out) {
    int gid = blockIdx.x * blockDim.x + threadIdx.x;     // one per (token, e-group)
    int tok = gid / THREADS_PER_TOK;                     // 0..4095
    int eg  = gid % THREADS_PER_TOK;                     // 0..31
    if (tok >= NTOK) return;

    int idx = X[tok];                                    // broadcast within 32-thread group
    int e0  = eg * VEC;

    // Strided reads down W's column `idx` (stride VOCAB floats between e's).
    // W (16.4 MB) is L2/L3 resident, so these are cache hits after warm-up.
    float4 v;
    v.x = W[(size_t)(e0 + 0) * VOCAB + idx];
    v.y = W[(size_t)(e0 + 1) * VOCAB + idx];
    v.z = W[(size_t)(e0 + 2) * VOCAB + idx];
    v.w = W[(size_t)(e0 + 3) * VOCAB + idx];

    // Coalesced vector store: consecutive threads write consecutive 16B chunks.
    *reinterpret_cast<float4*>(&out[(size_t)tok * EMBED + e0]) = v;
}

extern "C" void kernel_launch(void* const* d_in, const int* in_sizes, int n_in,
                              void* d_out, int out_size, void* d_ws, size_t ws_size,
                              hipStream_t stream) {
    const int*   X = (const int*)d_in[0];
    const float* W = (const float*)d_in[1];
    float*     out = (float*)d_out;

    const int total_threads = NTOK * THREADS_PER_TOK;    // 131072
    const int block = 256;
    const int grid  = (total_threads + block - 1) / block;  // 512
    embed_gather_kernel<<<grid, block, 0, stream>>>(X, W, out);
}